// Round 9
// baseline (1980.339 us; speedup 1.0000x reference)
//
#include <hip/hip_runtime.h>

#define B_ 64
#define P_ 196
#define ENC_ 2048
#define L_ 20
#define T_ 19
#define A_ 512
#define D_ 512
#define E_ 512
#define V_ 10000

// output offsets (float elements)
#define OFF_PREDS 0
#define OFF_CAPS  12160000
#define OFF_DLEN  12161280
#define OFF_ALPH  12161344
#define OFF_SIDX  12399680

// workspace offsets (bytes) — total ~104.5 MB
#define WS_SORT   0          /* 64 int */
#define WS_DLEN   1024
#define WS_CAPS   2048       /* 64*20 int */
#define WS_CNT    61440      /* 19*32 int last-finisher counters */
#define WS_DAS    114688     /* 64*512 f32 */
#define WS_GATE   245760     /* 64*2048 f32 */
#define WS_HB0    770048     /* 64*512 bf16 */
#define WS_HB1    835584
#define WS_C      901120     /* 64*512 f32 */
#define WS_CTXG   1032192    /* 64*2048 bf16 */
#define WS_MEANB  1294336    /* 64*2048 bf16 */
#define WS_HIST   1556480    /* 1280*512 bf16 */
#define WS_EMB    2867200    /* 1216*512 bf16 */
#define WS_GPART  4194304    /* 8*64*2048 f32 = 4 MB */
#define WS_EPT    8388608    /* 12544*512 bf16 = 12.85 MB */
#define WS_WEAT   21233664   /* 512*2048 bf16 */
#define WS_WHG    23330816   /* 2560*512 bf16 */
#define WS_W2I    25952256   /* 2048*3072 bf16 */
#define WS_WOB    38535168   /* 10112*512 bf16 */
#define WS_WINIT  48889856   /* 1024*2048 bf16 */
#define WS_ENCS   53084160   /* 12544*2048 bf16 = 51.38 MB -> end 104464384 */

typedef __attribute__((ext_vector_type(8))) short short8v;
typedef __attribute__((ext_vector_type(4))) float f32x4;
typedef unsigned int uint32;
typedef unsigned short ushort16;

__device__ __forceinline__ float ftanh(float x){ float e=__expf(2.f*x); return 1.f-2.f/(e+1.f); }
__device__ __forceinline__ float fsigm(float x){ return 1.f/(1.f+__expf(-x)); }
__device__ __forceinline__ ushort16 f2b(float f){
    uint32 u = __float_as_uint(f);
    uint32 r = (u + 0x7FFFu + ((u >> 16) & 1u)) >> 16;
    return (ushort16)r;
}
__device__ __forceinline__ uint32 pack_b2(float a, float b){
    return (uint32)f2b(a) | ((uint32)f2b(b) << 16);
}
__device__ __forceinline__ float b2f_lo(uint32 w){ return __uint_as_float(w << 16); }
__device__ __forceinline__ float b2f_hi(uint32 w){ return __uint_as_float(w & 0xFFFF0000u); }
__device__ __forceinline__ float b1f(ushort16 x){ return __uint_as_float((uint32)x << 16); }

// ---------------------------------------------------------------- parallel rank sort + meta
__global__ void k_sort(const int* __restrict__ cap_len, const int* __restrict__ captions,
                       float* __restrict__ out, int* __restrict__ wsi)
{
    __shared__ int len_s[B_];
    int tid = threadIdx.x;        // 64 threads
    int len = cap_len[tid];
    len_s[tid] = len;
    __syncthreads();
    int rank = 0;
#pragma unroll
    for (int j = 0; j < B_; ++j) {
        int lj = len_s[j];
        rank += (lj > len) || (lj == len && j < tid);
    }
    wsi[WS_SORT / 4 + rank] = tid;
    wsi[WS_DLEN / 4 + rank] = len - 1;
    out[OFF_SIDX + rank] = (float)tid;
    out[OFF_DLEN + rank] = (float)(len - 1);
#pragma unroll
    for (int l = 0; l < L_; ++l) {
        int cv = captions[tid * L_ + l];
        wsi[WS_CAPS / 4 + rank * L_ + l] = cv;
        out[OFF_CAPS + rank * L_ + l] = (float)cv;
    }
}

// ---------------------------------------------------------------- gathered sorted bf16 copy of enc
__global__ __launch_bounds__(256) void k_cast_enc(const float* __restrict__ enc,
                                                  const int* __restrict__ sortidx,
                                                  ushort16* __restrict__ encS)
{
    int p = blockIdx.x, b = blockIdx.y;
    int c0 = threadIdx.x * 8;
    const float* s = enc + ((long)sortidx[b] * P_ + p) * ENC_ + c0;
    float4 f0 = *(const float4*)s;
    float4 f1 = *(const float4*)(s + 4);
    uint4 v; v.x = pack_b2(f0.x, f0.y); v.y = pack_b2(f0.z, f0.w);
    v.z = pack_b2(f1.x, f1.y); v.w = pack_b2(f1.z, f1.w);
    *(uint4*)(encS + ((long)b * P_ + p) * ENC_ + c0) = v;
}

// ---------------------------------------------------------------- transpose+cast f32[R][C] -> bf16[C][R]
__global__ __launch_bounds__(256) void k_transpose(const float* __restrict__ src, int R, int C,
                                                   ushort16* __restrict__ dst)
{
    __shared__ float tile[64][65];
    int c0 = blockIdx.x * 64, r0 = blockIdx.y * 64;
    int lx = threadIdx.x & 63, ly = threadIdx.x >> 6;
#pragma unroll
    for (int i = 0; i < 16; ++i) {
        int r = ly * 16 + i;
        tile[lx][r] = src[(long)(r0 + r) * C + c0 + lx];
    }
    __syncthreads();
#pragma unroll
    for (int i = 0; i < 16; ++i) {
        int cr = ly * 16 + i;
        dst[(long)(c0 + cr) * R + r0 + lx] = f2b(tile[cr][lx]);
    }
}

// ---------------------------------------------------------------- pack W2i[r=4d+q][3072] = [Wih row | Whh row]
__global__ __launch_bounds__(256) void k_pack_w2i(const float* __restrict__ WIH,
                                                  const float* __restrict__ WHH,
                                                  ushort16* __restrict__ dst)
{
    int r = blockIdx.x;               // 0..2047
    int d = r >> 2, q = r & 3;
    int n = q * 512 + d;
    for (int cch = threadIdx.x; cch < 384; cch += 256) {
        int kof = cch * 8;
        const float* s = (kof < 2560) ? (WIH + (long)n * 2560 + kof)
                                      : (WHH + (long)n * 512 + (kof - 2560));
        float4 f0 = *(const float4*)s;
        float4 f1 = *(const float4*)(s + 4);
        uint4 v; v.x = pack_b2(f0.x, f0.y); v.y = pack_b2(f0.z, f0.w);
        v.z = pack_b2(f1.x, f1.y); v.w = pack_b2(f1.z, f1.w);
        *(uint4*)(dst + (long)r * 3072 + kof) = v;
    }
}

// ---------------------------------------------------------------- cast W_out rows (zero-pad >=10000)
__global__ __launch_bounds__(256) void k_cast_wout(const float* __restrict__ src,
                                                   ushort16* __restrict__ dst)
{
    int r = blockIdx.x;               // 0..10111
    int k = threadIdx.x * 2;
    uint32 v = 0;
    if (r < V_) {
        float2 f = *(const float2*)(src + (long)r * 512 + k);
        v = pack_b2(f.x, f.y);
    }
    *(uint32*)(dst + (long)r * 512 + k) = v;
}

// ---------------------------------------------------------------- gather+cast embeddings
__global__ __launch_bounds__(256) void k_cast_emb(const float* __restrict__ embedding,
                                                  const int* __restrict__ caps,
                                                  ushort16* __restrict__ dst)
{
    int m = blockIdx.x;                       // 0..1215, m = t*64+b
    int tok = caps[(m & 63) * L_ + (m >> 6)];
    int k = threadIdx.x * 2;
    float2 v = *(const float2*)(embedding + (long)tok * E_ + k);
    *(uint32*)(dst + (long)m * E_ + k) = pack_b2(v.x, v.y);
}

// ---------------------------------------------------------------- mean feats (bf16 src) -> bf16
__global__ __launch_bounds__(256) void k_mean(const ushort16* __restrict__ encS,
                                              ushort16* __restrict__ meanB)
{
    int b = blockIdx.x;
    int e = blockIdx.y * 256 + threadIdx.x;
    const ushort16* p = encS + (long)b * P_ * ENC_ + e;
    float s = 0.f;
    for (int i = 0; i < P_; ++i) s += b1f(p[(long)i * ENC_]);
    meanB[b * ENC_ + e] = f2b(s * (1.f / (float)P_));
}

// ---------------------------------------------------------------- bf16 MFMA GEMM
// EPI 1: bf16 C = v+bias
// EPI 2: gn<512 -> das[gm*512+gn]=v+bias; else gate[gm*2048+gn-512]=sigmoid(v+bias2)
// EPI 6: gn<512 -> hb=f2b(v+bias); else c=v+bias2
// EPI 7: b=gm&63,tt=gm>>6; coverage over valid rows only (tt<T_): preds=(tt<dlen)?v+bias:0
template<int BM, int BN, int WM, int WN, int EPI>
__global__ __launch_bounds__(256) void mgemm(
    const ushort16* __restrict__ Amat, int lda1,
    const ushort16* __restrict__ Bmat, int ldb,
    void* __restrict__ Cout, void* __restrict__ Cout2, int ldc, int N, int K,
    const float* __restrict__ bias, const float* __restrict__ bias2,
    const int* __restrict__ dlen)
{
    __shared__ __align__(16) ushort16 As[BM * 64];
    __shared__ __align__(16) ushort16 Bs[BN * 64];
    const int tid = threadIdx.x;
    const int m0 = blockIdx.y * BM, n0 = blockIdx.x * BN;
    const int lane = tid & 63, wid = tid >> 6;
    constexpr int NWC = BN / WN;
    const int wr = wid / NWC, wc = wid % NWC;
    constexpr int FM = WM / 16, FN = WN / 16;
    f32x4 acc[FM][FN] = {};

    for (int k0 = 0; k0 < K; k0 += 64) {
        for (int i = tid; i < BM * 8; i += 256) {
            int r = i >> 3, ck = i & 7;
            uint4 val = *(const uint4*)(Amat + (long)(m0 + r) * lda1 + k0 + ck * 8);
            int bo = (r * 128 + ck * 16) ^ ((r & 7) << 4);
            *(uint4*)((char*)As + bo) = val;
        }
        for (int i = tid; i < BN * 8; i += 256) {
            int r = i >> 3, ck = i & 7;
            uint4 val = *(const uint4*)(Bmat + (long)(n0 + r) * ldb + k0 + ck * 8);
            int bo = (r * 128 + ck * 16) ^ ((r & 7) << 4);
            *(uint4*)((char*)Bs + bo) = val;
        }
        __syncthreads();
#pragma unroll
        for (int kk = 0; kk < 64; kk += 32) {
            short8v af[FM], bfr[FN];
#pragma unroll
            for (int f = 0; f < FM; ++f) {
                int r = wr * WM + f * 16 + (lane & 15);
                int bo = (r * 128 + (kk + ((lane >> 4) << 3)) * 2) ^ ((r & 7) << 4);
                af[f] = *(const short8v*)((const char*)As + bo);
            }
#pragma unroll
            for (int f = 0; f < FN; ++f) {
                int r = wc * WN + f * 16 + (lane & 15);
                int bo = (r * 128 + (kk + ((lane >> 4) << 3)) * 2) ^ ((r & 7) << 4);
                bfr[f] = *(const short8v*)((const char*)Bs + bo);
            }
#pragma unroll
            for (int fm = 0; fm < FM; ++fm)
#pragma unroll
                for (int fn = 0; fn < FN; ++fn)
                    acc[fm][fn] = __builtin_amdgcn_mfma_f32_16x16x32_bf16(
                        af[fm], bfr[fn], acc[fm][fn], 0, 0, 0);
        }
        __syncthreads();
    }

    int rr = lane >> 4, cc = lane & 15;
#pragma unroll
    for (int fm = 0; fm < FM; ++fm) {
#pragma unroll
        for (int fn = 0; fn < FN; ++fn) {
#pragma unroll
            for (int r = 0; r < 4; ++r) {
                int gm = m0 + wr * WM + fm * 16 + rr * 4 + r;
                int gn = n0 + wc * WN + fn * 16 + cc;
                float v = acc[fm][fn][r];
                if (EPI == 1) {
                    ((ushort16*)Cout)[(long)gm * ldc + gn] = f2b(v + bias[gn]);
                } else if (EPI == 2) {
                    if (gn < 512) ((float*)Cout)[gm * 512 + gn] = v + bias[gn];
                    else ((float*)Cout2)[gm * ENC_ + (gn - 512)] = fsigm(v + bias2[gn - 512]);
                } else if (EPI == 6) {
                    if (gn < 512) ((ushort16*)Cout)[gm * 512 + gn] = f2b(v + bias[gn]);
                    else ((float*)Cout2)[gm * 512 + (gn - 512)] = v + bias2[gn - 512];
                } else if (EPI == 7) {
                    int bq = gm & 63, tt = gm >> 6;
                    if (gn < N && tt < T_)   // tt<T_ guard: rows >=1216 are padding (R8 bug: clobbered OFF_CAPS)
                        ((float*)Cout)[((long)bq * T_ + tt) * V_ + gn] =
                            (tt < dlen[bq]) ? v + bias[gn] : 0.f;
                }
            }
        }
    }
}

// ---------------------------------------------------------------- attention: scores+softmax+alpha+ctx
// grid 64 (one block per b), 512 threads (8 waves)
__global__ __launch_bounds__(512) void k_att(
    const float* __restrict__ das, const float* __restrict__ gate,
    const float* __restrict__ Wfa, const float* __restrict__ bfa,
    const ushort16* __restrict__ ept, const ushort16* __restrict__ encS,
    const int* __restrict__ dlen,
    ushort16* __restrict__ ctxg, float* __restrict__ out, int t)
{
    int b = blockIdx.x;
    int tid = threadIdx.x;
    if (t >= dlen[b]) {
        // full-coverage zero of this alpha row (replaces host-side memset)
        if (tid < P_) out[OFF_ALPH + ((long)b * T_ + t) * P_ + tid] = 0.f;
        return;
    }
    __shared__ float al[P_ + 4];
    __shared__ float red[512];
    int lane = tid & 63, wv = tid >> 6;
    // scores: waves split p, lanes split a
    float wf8[8], da8[8];
    {
        const float* wp = Wfa + lane * 8;
        const float* dp = das + b * 512 + lane * 8;
#pragma unroll
        for (int j = 0; j < 8; ++j) { wf8[j] = wp[j]; da8[j] = dp[j]; }
    }
    float b0 = bfa[0];
    for (int p = wv; p < P_; p += 8) {
        uint4 u = *(const uint4*)(ept + ((long)(b * P_ + p)) * 512 + lane * 8);
        float s = 0.f;
        s += wf8[0] * ftanh(b2f_lo(u.x) + da8[0]);
        s += wf8[1] * ftanh(b2f_hi(u.x) + da8[1]);
        s += wf8[2] * ftanh(b2f_lo(u.y) + da8[2]);
        s += wf8[3] * ftanh(b2f_hi(u.y) + da8[3]);
        s += wf8[4] * ftanh(b2f_lo(u.z) + da8[4]);
        s += wf8[5] * ftanh(b2f_hi(u.z) + da8[5]);
        s += wf8[6] * ftanh(b2f_lo(u.w) + da8[6]);
        s += wf8[7] * ftanh(b2f_hi(u.w) + da8[7]);
#pragma unroll
        for (int off = 32; off > 0; off >>= 1) s += __shfl_xor(s, off);
        if (lane == 0) al[p] = s + b0;
    }
    __syncthreads();
    // softmax over 196 (512-thread tree)
    float sc = (tid < P_) ? al[tid] : -1e30f;
    red[tid] = sc;
    __syncthreads();
    for (int s = 256; s > 0; s >>= 1) {
        if (tid < s) red[tid] = fmaxf(red[tid], red[tid + s]);
        __syncthreads();
    }
    float mx = red[0];
    __syncthreads();
    float e = (tid < P_) ? __expf(sc - mx) : 0.f;
    red[tid] = e;
    __syncthreads();
    for (int s = 256; s > 0; s >>= 1) {
        if (tid < s) red[tid] += red[tid + s];
        __syncthreads();
    }
    float inv = 1.f / red[0];
    __syncthreads();
    if (tid < P_) al[tid] = e * inv;
    __syncthreads();
    if (tid < P_)
        out[OFF_ALPH + ((long)b * T_ + t) * P_ + tid] = al[tid];
    // ctx: 4 bf16 cols per thread from encS (8B coalesced loads)
    int e0 = tid * 4;
    long base = ((long)b * P_) * ENC_ + e0;
    float a0 = 0.f, a1 = 0.f, a2 = 0.f, a3 = 0.f;
#pragma unroll 4
    for (int p = 0; p < P_; ++p) {
        uint2 v = *(const uint2*)(encS + base + (long)p * ENC_);
        float alp = al[p];
        a0 += alp * b2f_lo(v.x); a1 += alp * b2f_hi(v.x);
        a2 += alp * b2f_lo(v.y); a3 += alp * b2f_hi(v.y);
    }
    const float* gp = gate + b * ENC_ + e0;
    uint2 o;
    o.x = pack_b2(gp[0] * a0, gp[1] * a1);
    o.y = pack_b2(gp[2] * a2, gp[3] * a3);
    *(uint2*)(ctxg + b * ENC_ + e0) = o;
}

// ---------------------------------------------------------------- gates GEMM split-K + last-finisher LSTM
// 256 blocks: (nt 0..31) x (ks 0..7). Last block of each nt group reduces
// the 8 partials for its 16 d-units and runs the LSTM pointwise.
__global__ __launch_bounds__(256) void k_gates(
    const ushort16* __restrict__ embB, const ushort16* __restrict__ ctxg,
    const ushort16* __restrict__ hin,  const ushort16* __restrict__ W2i,
    float* __restrict__ gpart,
    const float* __restrict__ bIH, const float* __restrict__ bHH,
    const int* __restrict__ dlen, float* __restrict__ c,
    ushort16* __restrict__ hout, ushort16* __restrict__ histB,
    int* cnt, int t)
{
    __shared__ __align__(16) ushort16 As[64 * 64];
    __shared__ __align__(16) ushort16 Bs[64 * 64];
    __shared__ int sLast;
    const int tid = threadIdx.x;
    const int nt = blockIdx.x >> 3, ks = blockIdx.x & 7;
    const int n0 = nt * 64, kbeg = ks * 384;
    const int lane = tid & 63, wid = tid >> 6;
    const int wr = wid >> 1, wc = wid & 1;
    f32x4 acc[2][2] = {};

    for (int k0 = kbeg; k0 < kbeg + 384; k0 += 64) {
        for (int i = tid; i < 512; i += 256) {
            int r = i >> 3, ck = i & 7;
            int kk = k0 + ck * 8;
            const ushort16* src;
            if (kk < 512)       src = embB + ((long)(t * 64 + r)) * 512 + kk;
            else if (kk < 2560) src = ctxg + (long)r * ENC_ + (kk - 512);
            else                src = hin + (long)r * 512 + (kk - 2560);
            uint4 val = *(const uint4*)src;
            int bo = (r * 128 + ck * 16) ^ ((r & 7) << 4);
            *(uint4*)((char*)As + bo) = val;
        }
        for (int i = tid; i < 512; i += 256) {
            int r = i >> 3, ck = i & 7;
            uint4 val = *(const uint4*)(W2i + (long)(n0 + r) * 3072 + k0 + ck * 8);
            int bo = (r * 128 + ck * 16) ^ ((r & 7) << 4);
            *(uint4*)((char*)Bs + bo) = val;
        }
        __syncthreads();
#pragma unroll
        for (int kk = 0; kk < 64; kk += 32) {
            short8v af[2], bfr[2];
#pragma unroll
            for (int f = 0; f < 2; ++f) {
                int r = wr * 32 + f * 16 + (lane & 15);
                int bo = (r * 128 + (kk + ((lane >> 4) << 3)) * 2) ^ ((r & 7) << 4);
                af[f] = *(const short8v*)((const char*)As + bo);
            }
#pragma unroll
            for (int f = 0; f < 2; ++f) {
                int r = wc * 32 + f * 16 + (lane & 15);
                int bo = (r * 128 + (kk + ((lane >> 4) << 3)) * 2) ^ ((r & 7) << 4);
                bfr[f] = *(const short8v*)((const char*)Bs + bo);
            }
#pragma unroll
            for (int fm = 0; fm < 2; ++fm)
#pragma unroll
                for (int fn = 0; fn < 2; ++fn)
                    acc[fm][fn] = __builtin_amdgcn_mfma_f32_16x16x32_bf16(
                        af[fm], bfr[fn], acc[fm][fn], 0, 0, 0);
        }
        __syncthreads();
    }
    int rr = lane >> 4, cc = lane & 15;
#pragma unroll
    for (int fm = 0; fm < 2; ++fm)
#pragma unroll
        for (int fn = 0; fn < 2; ++fn)
#pragma unroll
            for (int r = 0; r < 4; ++r) {
                int gm = wr * 32 + fm * 16 + rr * 4 + r;
                int gn = n0 + wc * 32 + fn * 16 + cc;
                gpart[((long)(ks * 64 + gm)) * ENC_ + gn] = acc[fm][fn][r];
            }
    __syncthreads();   // drain this block's partial stores (vmcnt 0)
    if (tid == 0) {
        __threadfence();  // release: make partials visible at device scope
        int a = __hip_atomic_fetch_add(&cnt[t * 32 + nt], 1,
                                       __ATOMIC_ACQ_REL, __HIP_MEMORY_SCOPE_AGENT);
        sLast = (a == 7);
        if (sLast) __threadfence();  // acquire: see other XCDs' partials
    }
    __syncthreads();
    if (sLast) {
        // LSTM pointwise for this nt's 16 d-units, all 64 b
#pragma unroll
        for (int it = 0; it < 4; ++it) {
            int idx = it * 256 + tid;         // 1024 = 64 b x 16 dl
            int b = idx >> 4, dl = idx & 15;
            int d = nt * 16 + dl;
            long off = (long)b * 512 + d;
            if (t < dlen[b]) {
                float s0 = 0.f, s1 = 0.f, s2 = 0.f, s3 = 0.f;
#pragma unroll
                for (int k2 = 0; k2 < 8; ++k2) {
                    float4 gp = *(const float4*)(gpart + ((long)(k2 * 64 + b)) * ENC_ + 4 * d);
                    s0 += gp.x; s1 += gp.y; s2 += gp.z; s3 += gp.w;
                }
                float g0 = s0 + bIH[d] + bHH[d];
                float g1 = s1 + bIH[512 + d] + bHH[512 + d];
                float g2v = s2 + bIH[1024 + d] + bHH[1024 + d];
                float g3 = s3 + bIH[1536 + d] + bHH[1536 + d];
                float i_ = fsigm(g0), f_ = fsigm(g1), gg = ftanh(g2v), o_ = fsigm(g3);
                float cn = f_ * c[off] + i_ * gg;
                float hn = o_ * ftanh(cn);
                c[off] = cn;
                ushort16 hv = f2b(hn);
                hout[off] = hv;
                histB[((long)(t * 64 + b)) * 512 + d] = hv;
            } else {
                ushort16 hv = hin[off];
                hout[off] = hv;
                histB[((long)(t * 64 + b)) * 512 + d] = hv;
            }
        }
    }
}

// ---------------------------------------------------------------- launch
extern "C" void kernel_launch(void* const* d_in, const int* in_sizes, int n_in,
                              void* d_out, int out_size, void* d_ws, size_t ws_size,
                              hipStream_t stream)
{
    (void)in_sizes; (void)n_in; (void)out_size; (void)ws_size;
    const float* enc      = (const float*)d_in[0];
    const int*   captions = (const int*)d_in[1];
    const int*   caplen   = (const int*)d_in[2];
    const float* Wemb     = (const float*)d_in[3];
    const float* Wea = (const float*)d_in[4];  const float* bea = (const float*)d_in[5];
    const float* Wda = (const float*)d_in[6];  const float* bda = (const float*)d_in[7];
    const float* Wfa = (const float*)d_in[8];  const float* bfa = (const float*)d_in[9];
    const float* Wih = (const float*)d_in[10]; const float* bih = (const float*)d_in[11];
    const float* Wic = (const float*)d_in[12]; const float* bic = (const float*)d_in[13];
    const float* Wbe = (const float*)d_in[14]; const float* bbe = (const float*)d_in[15];
    const float* WIH = (const float*)d_in[16]; const float* bIH = (const float*)d_in[17];
    const float* WHH = (const float*)d_in[18]; const float* bHH = (const float*)d_in[19];
    const float* Wout = (const float*)d_in[20]; const float* bout = (const float*)d_in[21];

    float* out = (float*)d_out;
    char*  ws  = (char*)d_ws;
    int*   wsi = (int*)ws;
    const int* dlen = wsi + WS_DLEN / 4;
    const int* sortidx = wsi + WS_SORT / 4;
    int*   cnt     = (int*)(ws + WS_CNT);
    float* das     = (float*)(ws + WS_DAS);
    float* gate    = (float*)(ws + WS_GATE);
    ushort16* hb0  = (ushort16*)(ws + WS_HB0);
    ushort16* hb1  = (ushort16*)(ws + WS_HB1);
    float* c       = (float*)(ws + WS_C);
    ushort16* ctxg = (ushort16*)(ws + WS_CTXG);
    ushort16* meanB= (ushort16*)(ws + WS_MEANB);
    ushort16* histB= (ushort16*)(ws + WS_HIST);
    ushort16* embB = (ushort16*)(ws + WS_EMB);
    float* gpart   = (float*)(ws + WS_GPART);
    ushort16* ept  = (ushort16*)(ws + WS_EPT);
    ushort16* WeaT = (ushort16*)(ws + WS_WEAT);
    ushort16* Whg  = (ushort16*)(ws + WS_WHG);
    ushort16* W2i  = (ushort16*)(ws + WS_W2I);
    ushort16* WoB  = (ushort16*)(ws + WS_WOB);
    ushort16* WInit= (ushort16*)(ws + WS_WINIT);
    ushort16* encS = (ushort16*)(ws + WS_ENCS);

    hipMemsetAsync(cnt, 0, T_ * 32 * 4, stream);   // last-finisher counters

    k_sort<<<1, 64, 0, stream>>>(caplen, captions, out, wsi);
    k_cast_enc<<<dim3(196, 64), 256, 0, stream>>>(enc, sortidx, encS);
    // one-time weight prep
    k_transpose<<<dim3(8, 32), 256, 0, stream>>>(Wea, ENC_, A_, WeaT);               // [a][e]
    k_transpose<<<dim3(8, 8),  256, 0, stream>>>(Wda, D_, A_, Whg);                  // rows 0..511
    k_transpose<<<dim3(32, 8), 256, 0, stream>>>(Wbe, D_, ENC_, Whg + 512 * 512);    // rows 512..2559
    k_transpose<<<dim3(8, 32), 256, 0, stream>>>(Wih, ENC_, D_, WInit);              // rows 0..511
    k_transpose<<<dim3(8, 32), 256, 0, stream>>>(Wic, ENC_, D_, WInit + 512 * 2048); // rows 512..1023
    k_pack_w2i<<<2048, 256, 0, stream>>>(WIH, WHH, W2i);
    k_cast_wout<<<10112, 256, 0, stream>>>(Wout, WoB);
    k_cast_emb<<<1216, 256, 0, stream>>>(Wemb, wsi + WS_CAPS / 4, embB);
    k_mean<<<dim3(64, 8), 256, 0, stream>>>(encS, meanB);

    // h0 | c0 = meanB @ WInit^T
    mgemm<64, 64, 32, 32, 6><<<dim3(16, 1), 256, 0, stream>>>(
        meanB, ENC_, WInit, ENC_, hb0, c, 0, 1024, ENC_, bih, bic, nullptr);
    // enc_proj -> ept bf16 [b*196+p][a]  (A = encS bf16, already sorted)
    mgemm<128, 128, 64, 64, 1><<<dim3(4, 98), 256, 0, stream>>>(
        encS, ENC_, WeaT, ENC_, ept, nullptr, A_, A_, ENC_, bea, nullptr, nullptr);

    for (int t = 0; t < T_; ++t) {
        ushort16* hcur = (t & 1) ? hb1 : hb0;
        ushort16* hnxt = (t & 1) ? hb0 : hb1;
        // das | beta-gate (MFMA, 40 blocks)
        mgemm<64, 64, 32, 32, 2><<<dim3(40, 1), 256, 0, stream>>>(
            hcur, D_, Whg, D_, das, gate, 0, 2560, D_, bda, bbe, nullptr);
        k_att<<<64, 512, 0, stream>>>(das, gate, Wfa, bfa, ept, encS, dlen, ctxg, out, t);
        k_gates<<<256, 256, 0, stream>>>(embB, ctxg, hcur, W2i, gpart,
                                         bIH, bHH, dlen, c, hnxt, histB, cnt, t);
    }
    // all preds in one GEMM (valid rows only; masked rows write zeros)
    mgemm<128, 128, 64, 64, 7><<<dim3(79, 10), 256, 0, stream>>>(
        histB, D_, WoB, D_, out + OFF_PREDS, nullptr, 0, V_, D_, bout, nullptr,
        dlen);
}

// Round 10
// 1657.452 us; speedup vs baseline: 1.1948x; 1.1948x over previous
//
#include <hip/hip_runtime.h>

#define B_ 64
#define P_ 196
#define ENC_ 2048
#define L_ 20
#define T_ 19
#define A_ 512
#define D_ 512
#define E_ 512
#define V_ 10000

// output offsets (float elements)
#define OFF_PREDS 0
#define OFF_CAPS  12160000
#define OFF_DLEN  12161280
#define OFF_ALPH  12161344
#define OFF_SIDX  12399680

// workspace offsets (bytes) — total ~104.5 MB
#define WS_SORT   0          /* 64 int */
#define WS_DLEN   1024
#define WS_CAPS   2048       /* 64*20 int */
#define WS_DAS    114688     /* 64*512 f32 */
#define WS_GATE   245760     /* 64*2048 f32 */
#define WS_HB0    770048     /* 64*512 bf16 */
#define WS_HB1    835584
#define WS_C      901120     /* 64*512 f32 */
#define WS_CTXG   1032192    /* 64*2048 bf16 */
#define WS_MEANB  1294336    /* 64*2048 bf16 */
#define WS_HIST   1556480    /* 1280*512 bf16 */
#define WS_EMB    2867200    /* 1216*512 bf16 */
#define WS_GPART  4194304    /* 8*64*2048 f32 = 4 MB */
#define WS_EPT    8388608    /* 12544*512 bf16 = 12.85 MB */
#define WS_WEAT   21233664   /* 512*2048 bf16 */
#define WS_WHG    23330816   /* 2560*512 bf16 */
#define WS_W2I    25952256   /* 2048*3072 bf16 */
#define WS_WOB    38535168   /* 10112*512 bf16 */
#define WS_WINIT  48889856   /* 1024*2048 bf16 */
#define WS_ENCS   53084160   /* 12544*2048 bf16 = 51.38 MB -> end 104464384 */

typedef __attribute__((ext_vector_type(8))) short short8v;
typedef __attribute__((ext_vector_type(4))) float f32x4;
typedef unsigned int uint32;
typedef unsigned short ushort16;

__device__ __forceinline__ float ftanh(float x){ float e=__expf(2.f*x); return 1.f-2.f/(e+1.f); }
__device__ __forceinline__ float fsigm(float x){ return 1.f/(1.f+__expf(-x)); }
__device__ __forceinline__ ushort16 f2b(float f){
    uint32 u = __float_as_uint(f);
    uint32 r = (u + 0x7FFFu + ((u >> 16) & 1u)) >> 16;
    return (ushort16)r;
}
__device__ __forceinline__ uint32 pack_b2(float a, float b){
    return (uint32)f2b(a) | ((uint32)f2b(b) << 16);
}
__device__ __forceinline__ float b2f_lo(uint32 w){ return __uint_as_float(w << 16); }
__device__ __forceinline__ float b2f_hi(uint32 w){ return __uint_as_float(w & 0xFFFF0000u); }
__device__ __forceinline__ float b1f(ushort16 x){ return __uint_as_float((uint32)x << 16); }

// ---------------------------------------------------------------- parallel rank sort + meta
__global__ void k_sort(const int* __restrict__ cap_len, const int* __restrict__ captions,
                       float* __restrict__ out, int* __restrict__ wsi)
{
    __shared__ int len_s[B_];
    int tid = threadIdx.x;        // 64 threads
    int len = cap_len[tid];
    len_s[tid] = len;
    __syncthreads();
    int rank = 0;
#pragma unroll
    for (int j = 0; j < B_; ++j) {
        int lj = len_s[j];
        rank += (lj > len) || (lj == len && j < tid);
    }
    wsi[WS_SORT / 4 + rank] = tid;
    wsi[WS_DLEN / 4 + rank] = len - 1;
    out[OFF_SIDX + rank] = (float)tid;
    out[OFF_DLEN + rank] = (float)(len - 1);
#pragma unroll
    for (int l = 0; l < L_; ++l) {
        int cv = captions[tid * L_ + l];
        wsi[WS_CAPS / 4 + rank * L_ + l] = cv;
        out[OFF_CAPS + rank * L_ + l] = (float)cv;
    }
}

// ---------------------------------------------------------------- gathered sorted bf16 copy of enc
__global__ __launch_bounds__(256) void k_cast_enc(const float* __restrict__ enc,
                                                  const int* __restrict__ sortidx,
                                                  ushort16* __restrict__ encS)
{
    int p = blockIdx.x, b = blockIdx.y;
    int c0 = threadIdx.x * 8;
    const float* s = enc + ((long)sortidx[b] * P_ + p) * ENC_ + c0;
    float4 f0 = *(const float4*)s;
    float4 f1 = *(const float4*)(s + 4);
    uint4 v; v.x = pack_b2(f0.x, f0.y); v.y = pack_b2(f0.z, f0.w);
    v.z = pack_b2(f1.x, f1.y); v.w = pack_b2(f1.z, f1.w);
    *(uint4*)(encS + ((long)b * P_ + p) * ENC_ + c0) = v;
}

// ---------------------------------------------------------------- merged transpose+cast (5 weights, 1 launch)
// ranges: [0,256) Wea | [256,320) Wda | [320,576) Wbe | [576,832) Wih | [832,1088) Wic
__global__ __launch_bounds__(256) void k_transpose_all(
    const float* __restrict__ Wea, const float* __restrict__ Wda,
    const float* __restrict__ Wbe, const float* __restrict__ Wih,
    const float* __restrict__ Wic,
    ushort16* __restrict__ WeaT, ushort16* __restrict__ Whg,
    ushort16* __restrict__ WInit)
{
    __shared__ float tile[64][65];
    int id = blockIdx.x;
    const float* src; ushort16* dst; int R, C, bx, by;
    if (id < 256)      { src = Wea; dst = WeaT;                R = 2048; C = 512;  int i2 = id;        bx = i2 & 7;  by = i2 >> 3; }
    else if (id < 320) { src = Wda; dst = Whg;                 R = 512;  C = 512;  int i2 = id - 256;  bx = i2 & 7;  by = i2 >> 3; }
    else if (id < 576) { src = Wbe; dst = Whg + 512 * 512;     R = 512;  C = 2048; int i2 = id - 320;  bx = i2 & 31; by = i2 >> 5; }
    else if (id < 832) { src = Wih; dst = WInit;               R = 2048; C = 512;  int i2 = id - 576;  bx = i2 & 7;  by = i2 >> 3; }
    else               { src = Wic; dst = WInit + 512 * 2048;  R = 2048; C = 512;  int i2 = id - 832;  bx = i2 & 7;  by = i2 >> 3; }
    int c0 = bx * 64, r0 = by * 64;
    int lx = threadIdx.x & 63, ly = threadIdx.x >> 6;
#pragma unroll
    for (int i = 0; i < 16; ++i) {
        int r = ly * 16 + i;
        tile[lx][r] = src[(long)(r0 + r) * C + c0 + lx];
    }
    __syncthreads();
#pragma unroll
    for (int i = 0; i < 16; ++i) {
        int cr = ly * 16 + i;
        dst[(long)(c0 + cr) * R + r0 + lx] = f2b(tile[cr][lx]);
    }
}

// ---------------------------------------------------------------- merged small prep: wout | emb | w2i
// ranges: [0,10112) wout rows | [10112,11328) emb rows | [11328,13376) w2i rows
__global__ __launch_bounds__(256) void k_prep_small(
    const float* __restrict__ Wout, const float* __restrict__ embedding,
    const int* __restrict__ caps, const float* __restrict__ WIH,
    const float* __restrict__ WHH,
    ushort16* __restrict__ WoB, ushort16* __restrict__ embB,
    ushort16* __restrict__ W2i)
{
    int id = blockIdx.x;
    if (id < 10112) {
        int r = id, k = threadIdx.x * 2;
        uint32 v = 0;
        if (r < V_) {
            float2 f = *(const float2*)(Wout + (long)r * 512 + k);
            v = pack_b2(f.x, f.y);
        }
        *(uint32*)(WoB + (long)r * 512 + k) = v;
    } else if (id < 11328) {
        int m = id - 10112;                    // m = t*64+b
        int tok = caps[(m & 63) * L_ + (m >> 6)];
        int k = threadIdx.x * 2;
        float2 v = *(const float2*)(embedding + (long)tok * E_ + k);
        *(uint32*)(embB + (long)m * E_ + k) = pack_b2(v.x, v.y);
    } else {
        int r = id - 11328;                    // 0..2047, r = 4d+q
        int d = r >> 2, q = r & 3;
        int n = q * 512 + d;
        for (int cch = threadIdx.x; cch < 384; cch += 256) {
            int kof = cch * 8;
            const float* s = (kof < 2560) ? (WIH + (long)n * 2560 + kof)
                                          : (WHH + (long)n * 512 + (kof - 2560));
            float4 f0 = *(const float4*)s;
            float4 f1 = *(const float4*)(s + 4);
            uint4 v; v.x = pack_b2(f0.x, f0.y); v.y = pack_b2(f0.z, f0.w);
            v.z = pack_b2(f1.x, f1.y); v.w = pack_b2(f1.z, f1.w);
            *(uint4*)(W2i + (long)r * 3072 + kof) = v;
        }
    }
}

// ---------------------------------------------------------------- mean feats (bf16 src) -> bf16
__global__ __launch_bounds__(256) void k_mean(const ushort16* __restrict__ encS,
                                              ushort16* __restrict__ meanB)
{
    int b = blockIdx.x;
    int e = blockIdx.y * 256 + threadIdx.x;
    const ushort16* p = encS + (long)b * P_ * ENC_ + e;
    float s = 0.f;
    for (int i = 0; i < P_; ++i) s += b1f(p[(long)i * ENC_]);
    meanB[b * ENC_ + e] = f2b(s * (1.f / (float)P_));
}

// ---------------------------------------------------------------- bf16 MFMA GEMM
// EPI 1: bf16 C = v+bias
// EPI 2: gn<512 -> das=v+bias; else gate=sigmoid(v+bias2)
// EPI 6: gn<512 -> hb=f2b(v+bias); else c=v+bias2
// EPI 7: b=gm&63,tt=gm>>6; tt<T_ guard; preds=(tt<dlen)?v+bias:0
// SWZ 1: enc_proj 1D grid 416 -> (x<4, y<98), same-A blocks on same XCD
// SWZ 2: pred     1D grid 800 -> (x<79, y<10), same-B blocks on same XCD
template<int BM, int BN, int WM, int WN, int EPI, int SWZ>
__global__ __launch_bounds__(256) void mgemm(
    const ushort16* __restrict__ Amat, int lda1,
    const ushort16* __restrict__ Bmat, int ldb,
    void* __restrict__ Cout, void* __restrict__ Cout2, int ldc, int N, int K,
    const float* __restrict__ bias, const float* __restrict__ bias2,
    const int* __restrict__ dlen)
{
    int bx, by;
    if (SWZ == 1) {
        int id = blockIdx.x;                 // 416 launched, 392 logical
        bx = (id & 31) >> 3;                 // 0..3, changes every 8 ids
        by = (id >> 5) * 8 + (id & 7);       // same-by blocks differ by 8 -> same XCD
        if (by >= 98) return;
    } else if (SWZ == 2) {
        int id = blockIdx.x;                 // 800 launched, 790 logical
        bx = (id / 80) * 8 + (id & 7);       // same-bx blocks differ by 8 -> same XCD
        by = (id >> 3) % 10;
        if (bx >= 79) return;
    } else { bx = blockIdx.x; by = blockIdx.y; }

    __shared__ __align__(16) ushort16 As[BM * 64];
    __shared__ __align__(16) ushort16 Bs[BN * 64];
    const int tid = threadIdx.x;
    const int m0 = by * BM, n0 = bx * BN;
    const int lane = tid & 63, wid = tid >> 6;
    constexpr int NWC = BN / WN;
    const int wr = wid / NWC, wc = wid % NWC;
    constexpr int FM = WM / 16, FN = WN / 16;
    f32x4 acc[FM][FN] = {};

    for (int k0 = 0; k0 < K; k0 += 64) {
        for (int i = tid; i < BM * 8; i += 256) {
            int r = i >> 3, ck = i & 7;
            uint4 val = *(const uint4*)(Amat + (long)(m0 + r) * lda1 + k0 + ck * 8);
            int bo = (r * 128 + ck * 16) ^ ((r & 7) << 4);
            *(uint4*)((char*)As + bo) = val;
        }
        for (int i = tid; i < BN * 8; i += 256) {
            int r = i >> 3, ck = i & 7;
            uint4 val = *(const uint4*)(Bmat + (long)(n0 + r) * ldb + k0 + ck * 8);
            int bo = (r * 128 + ck * 16) ^ ((r & 7) << 4);
            *(uint4*)((char*)Bs + bo) = val;
        }
        __syncthreads();
#pragma unroll
        for (int kk = 0; kk < 64; kk += 32) {
            short8v af[FM], bfr[FN];
#pragma unroll
            for (int f = 0; f < FM; ++f) {
                int r = wr * WM + f * 16 + (lane & 15);
                int bo = (r * 128 + (kk + ((lane >> 4) << 3)) * 2) ^ ((r & 7) << 4);
                af[f] = *(const short8v*)((const char*)As + bo);
            }
#pragma unroll
            for (int f = 0; f < FN; ++f) {
                int r = wc * WN + f * 16 + (lane & 15);
                int bo = (r * 128 + (kk + ((lane >> 4) << 3)) * 2) ^ ((r & 7) << 4);
                bfr[f] = *(const short8v*)((const char*)Bs + bo);
            }
#pragma unroll
            for (int fm = 0; fm < FM; ++fm)
#pragma unroll
                for (int fn = 0; fn < FN; ++fn)
                    acc[fm][fn] = __builtin_amdgcn_mfma_f32_16x16x32_bf16(
                        af[fm], bfr[fn], acc[fm][fn], 0, 0, 0);
        }
        __syncthreads();
    }

    int rr = lane >> 4, cc = lane & 15;
#pragma unroll
    for (int fm = 0; fm < FM; ++fm) {
#pragma unroll
        for (int fn = 0; fn < FN; ++fn) {
#pragma unroll
            for (int r = 0; r < 4; ++r) {
                int gm = m0 + wr * WM + fm * 16 + rr * 4 + r;
                int gn = n0 + wc * WN + fn * 16 + cc;
                float v = acc[fm][fn][r];
                if (EPI == 1) {
                    ((ushort16*)Cout)[(long)gm * ldc + gn] = f2b(v + bias[gn]);
                } else if (EPI == 2) {
                    if (gn < 512) ((float*)Cout)[gm * 512 + gn] = v + bias[gn];
                    else ((float*)Cout2)[gm * ENC_ + (gn - 512)] = fsigm(v + bias2[gn - 512]);
                } else if (EPI == 6) {
                    if (gn < 512) ((ushort16*)Cout)[gm * 512 + gn] = f2b(v + bias[gn]);
                    else ((float*)Cout2)[gm * 512 + (gn - 512)] = v + bias2[gn - 512];
                } else if (EPI == 7) {
                    int bq = gm & 63, tt = gm >> 6;
                    if (gn < N && tt < T_)   // tt<T_: rows >=1216 are padding (R8 bug lesson)
                        ((float*)Cout)[((long)bq * T_ + tt) * V_ + gn] =
                            (tt < dlen[bq]) ? v + bias[gn] : 0.f;
                }
            }
        }
    }
}

// ---------------------------------------------------------------- attention: scores+softmax+alpha+ctx
// grid (64, 2), 512 threads: scores+softmax redundant per eg; ctx split by eg (1024 cols each)
__global__ __launch_bounds__(512) void k_att(
    const float* __restrict__ das, const float* __restrict__ gate,
    const float* __restrict__ Wfa, const float* __restrict__ bfa,
    const ushort16* __restrict__ ept, const ushort16* __restrict__ encS,
    const int* __restrict__ dlen,
    ushort16* __restrict__ ctxg, float* __restrict__ out, int t)
{
    int b = blockIdx.x, eg = blockIdx.y;
    int tid = threadIdx.x;
    if (t >= dlen[b]) {
        if (eg == 0 && tid < P_) out[OFF_ALPH + ((long)b * T_ + t) * P_ + tid] = 0.f;
        return;
    }
    __shared__ float al[P_ + 4];
    __shared__ float red[512];
    int lane = tid & 63, wv = tid >> 6;
    // scores: waves split p, lanes split a
    float wf8[8], da8[8];
    {
        const float* wp = Wfa + lane * 8;
        const float* dp = das + b * 512 + lane * 8;
#pragma unroll
        for (int j = 0; j < 8; ++j) { wf8[j] = wp[j]; da8[j] = dp[j]; }
    }
    float b0 = bfa[0];
    for (int p = wv; p < P_; p += 8) {
        uint4 u = *(const uint4*)(ept + ((long)(b * P_ + p)) * 512 + lane * 8);
        float s = 0.f;
        s += wf8[0] * ftanh(b2f_lo(u.x) + da8[0]);
        s += wf8[1] * ftanh(b2f_hi(u.x) + da8[1]);
        s += wf8[2] * ftanh(b2f_lo(u.y) + da8[2]);
        s += wf8[3] * ftanh(b2f_hi(u.y) + da8[3]);
        s += wf8[4] * ftanh(b2f_lo(u.z) + da8[4]);
        s += wf8[5] * ftanh(b2f_hi(u.z) + da8[5]);
        s += wf8[6] * ftanh(b2f_lo(u.w) + da8[6]);
        s += wf8[7] * ftanh(b2f_hi(u.w) + da8[7]);
#pragma unroll
        for (int off = 32; off > 0; off >>= 1) s += __shfl_xor(s, off);
        if (lane == 0) al[p] = s + b0;
    }
    __syncthreads();
    // softmax over 196 (512-thread tree)
    float sc = (tid < P_) ? al[tid] : -1e30f;
    red[tid] = sc;
    __syncthreads();
    for (int s = 256; s > 0; s >>= 1) {
        if (tid < s) red[tid] = fmaxf(red[tid], red[tid + s]);
        __syncthreads();
    }
    float mx = red[0];
    __syncthreads();
    float e = (tid < P_) ? __expf(sc - mx) : 0.f;
    red[tid] = e;
    __syncthreads();
    for (int s = 256; s > 0; s >>= 1) {
        if (tid < s) red[tid] += red[tid + s];
        __syncthreads();
    }
    float inv = 1.f / red[0];
    __syncthreads();
    if (tid < P_) al[tid] = e * inv;
    __syncthreads();
    if (eg == 0 && tid < P_)
        out[OFF_ALPH + ((long)b * T_ + t) * P_ + tid] = al[tid];
    // ctx: 2 bf16 cols per thread from encS, this block's 1024-col slice
    int e0 = eg * 1024 + tid * 2;
    long base = ((long)b * P_) * ENC_ + e0;
    float a0 = 0.f, a1 = 0.f;
#pragma unroll 4
    for (int p = 0; p < P_; ++p) {
        uint32 v = *(const uint32*)(encS + base + (long)p * ENC_);
        float alp = al[p];
        a0 += alp * b2f_lo(v); a1 += alp * b2f_hi(v);
    }
    float2 g2 = *(const float2*)(gate + b * ENC_ + e0);
    *(uint32*)(ctxg + b * ENC_ + e0) = pack_b2(g2.x * a0, g2.y * a1);
}

// ---------------------------------------------------------------- gates GEMM split-K (256 blocks) — R7 proven
__global__ __launch_bounds__(256) void k_gates(
    const ushort16* __restrict__ embB, const ushort16* __restrict__ ctxg,
    const ushort16* __restrict__ hin,  const ushort16* __restrict__ W2i,
    float* __restrict__ gpart, int t)
{
    __shared__ __align__(16) ushort16 As[64 * 64];
    __shared__ __align__(16) ushort16 Bs[64 * 64];
    const int tid = threadIdx.x;
    const int nt = blockIdx.x >> 3, ks = blockIdx.x & 7;
    const int n0 = nt * 64, kbeg = ks * 384;
    const int lane = tid & 63, wid = tid >> 6;
    const int wr = wid >> 1, wc = wid & 1;
    f32x4 acc[2][2] = {};

    for (int k0 = kbeg; k0 < kbeg + 384; k0 += 64) {
        for (int i = tid; i < 512; i += 256) {
            int r = i >> 3, ck = i & 7;
            int kk = k0 + ck * 8;
            const ushort16* src;
            if (kk < 512)       src = embB + ((long)(t * 64 + r)) * 512 + kk;
            else if (kk < 2560) src = ctxg + (long)r * ENC_ + (kk - 512);
            else                src = hin + (long)r * 512 + (kk - 2560);
            uint4 val = *(const uint4*)src;
            int bo = (r * 128 + ck * 16) ^ ((r & 7) << 4);
            *(uint4*)((char*)As + bo) = val;
        }
        for (int i = tid; i < 512; i += 256) {
            int r = i >> 3, ck = i & 7;
            uint4 val = *(const uint4*)(W2i + (long)(n0 + r) * 3072 + k0 + ck * 8);
            int bo = (r * 128 + ck * 16) ^ ((r & 7) << 4);
            *(uint4*)((char*)Bs + bo) = val;
        }
        __syncthreads();
#pragma unroll
        for (int kk = 0; kk < 64; kk += 32) {
            short8v af[2], bfr[2];
#pragma unroll
            for (int f = 0; f < 2; ++f) {
                int r = wr * 32 + f * 16 + (lane & 15);
                int bo = (r * 128 + (kk + ((lane >> 4) << 3)) * 2) ^ ((r & 7) << 4);
                af[f] = *(const short8v*)((const char*)As + bo);
            }
#pragma unroll
            for (int f = 0; f < 2; ++f) {
                int r = wc * 32 + f * 16 + (lane & 15);
                int bo = (r * 128 + (kk + ((lane >> 4) << 3)) * 2) ^ ((r & 7) << 4);
                bfr[f] = *(const short8v*)((const char*)Bs + bo);
            }
#pragma unroll
            for (int fm = 0; fm < 2; ++fm)
#pragma unroll
                for (int fn = 0; fn < 2; ++fn)
                    acc[fm][fn] = __builtin_amdgcn_mfma_f32_16x16x32_bf16(
                        af[fm], bfr[fn], acc[fm][fn], 0, 0, 0);
        }
        __syncthreads();
    }
    int rr = lane >> 4, cc = lane & 15;
#pragma unroll
    for (int fm = 0; fm < 2; ++fm)
#pragma unroll
        for (int fn = 0; fn < 2; ++fn)
#pragma unroll
            for (int r = 0; r < 4; ++r) {
                int gm = wr * 32 + fm * 16 + rr * 4 + r;
                int gn = n0 + wc * 32 + fn * 16 + cc;
                gpart[((long)(ks * 64 + gm)) * ENC_ + gn] = acc[fm][fn][r];
            }
}

// ---------------------------------------------------------------- LSTM pointwise (reduce 8 partials) — R7 proven
__global__ __launch_bounds__(256) void k_lstm(
    const float* __restrict__ gpart,
    const float* __restrict__ bIH, const float* __restrict__ bHH,
    const int* __restrict__ dlen, float* __restrict__ c,
    const ushort16* __restrict__ hin, ushort16* __restrict__ hout,
    ushort16* __restrict__ histB, int t)
{
    int idx = blockIdx.x * 256 + threadIdx.x;   // 128 blocks -> 64 b x 512 d
    int b = idx >> 9, d = idx & 511;
    long off = (long)b * 512 + d;
    if (t < dlen[b]) {
        float s0 = 0.f, s1 = 0.f, s2 = 0.f, s3 = 0.f;
#pragma unroll
        for (int ks = 0; ks < 8; ++ks) {
            float4 gp = *(const float4*)(gpart + ((long)(ks * 64 + b)) * ENC_ + 4 * d);
            s0 += gp.x; s1 += gp.y; s2 += gp.z; s3 += gp.w;
        }
        float g0 = s0 + bIH[d] + bHH[d];
        float g1 = s1 + bIH[512 + d] + bHH[512 + d];
        float g2v = s2 + bIH[1024 + d] + bHH[1024 + d];
        float g3 = s3 + bIH[1536 + d] + bHH[1536 + d];
        float i_ = fsigm(g0), f_ = fsigm(g1), gg = ftanh(g2v), o_ = fsigm(g3);
        float cn = f_ * c[off] + i_ * gg;
        float hn = o_ * ftanh(cn);
        c[off] = cn;
        ushort16 hv = f2b(hn);
        hout[off] = hv;
        histB[((long)(t * 64 + b)) * 512 + d] = hv;
    } else {
        hout[off] = hin[off];
    }
}

// ---------------------------------------------------------------- launch
extern "C" void kernel_launch(void* const* d_in, const int* in_sizes, int n_in,
                              void* d_out, int out_size, void* d_ws, size_t ws_size,
                              hipStream_t stream)
{
    (void)in_sizes; (void)n_in; (void)out_size; (void)ws_size;
    const float* enc      = (const float*)d_in[0];
    const int*   captions = (const int*)d_in[1];
    const int*   caplen   = (const int*)d_in[2];
    const float* Wemb     = (const float*)d_in[3];
    const float* Wea = (const float*)d_in[4];  const float* bea = (const float*)d_in[5];
    const float* Wda = (const float*)d_in[6];  const float* bda = (const float*)d_in[7];
    const float* Wfa = (const float*)d_in[8];  const float* bfa = (const float*)d_in[9];
    const float* Wih = (const float*)d_in[10]; const float* bih = (const float*)d_in[11];
    const float* Wic = (const float*)d_in[12]; const float* bic = (const float*)d_in[13];
    const float* Wbe = (const float*)d_in[14]; const float* bbe = (const float*)d_in[15];
    const float* WIH = (const float*)d_in[16]; const float* bIH = (const float*)d_in[17];
    const float* WHH = (const float*)d_in[18]; const float* bHH = (const float*)d_in[19];
    const float* Wout = (const float*)d_in[20]; const float* bout = (const float*)d_in[21];

    float* out = (float*)d_out;
    char*  ws  = (char*)d_ws;
    int*   wsi = (int*)ws;
    const int* dlen = wsi + WS_DLEN / 4;
    const int* sortidx = wsi + WS_SORT / 4;
    float* das     = (float*)(ws + WS_DAS);
    float* gate    = (float*)(ws + WS_GATE);
    ushort16* hb0  = (ushort16*)(ws + WS_HB0);
    ushort16* hb1  = (ushort16*)(ws + WS_HB1);
    float* c       = (float*)(ws + WS_C);
    ushort16* ctxg = (ushort16*)(ws + WS_CTXG);
    ushort16* meanB= (ushort16*)(ws + WS_MEANB);
    ushort16* histB= (ushort16*)(ws + WS_HIST);
    ushort16* embB = (ushort16*)(ws + WS_EMB);
    float* gpart   = (float*)(ws + WS_GPART);
    ushort16* ept  = (ushort16*)(ws + WS_EPT);
    ushort16* WeaT = (ushort16*)(ws + WS_WEAT);
    ushort16* Whg  = (ushort16*)(ws + WS_WHG);
    ushort16* W2i  = (ushort16*)(ws + WS_W2I);
    ushort16* WoB  = (ushort16*)(ws + WS_WOB);
    ushort16* WInit= (ushort16*)(ws + WS_WINIT);
    ushort16* encS = (ushort16*)(ws + WS_ENCS);

    k_sort<<<1, 64, 0, stream>>>(caplen, captions, out, wsi);
    k_cast_enc<<<dim3(196, 64), 256, 0, stream>>>(enc, sortidx, encS);
    k_transpose_all<<<1088, 256, 0, stream>>>(Wea, Wda, Wbe, Wih, Wic, WeaT, Whg, WInit);
    k_prep_small<<<13376, 256, 0, stream>>>(Wout, Wemb, wsi + WS_CAPS / 4, WIH, WHH,
                                            WoB, embB, W2i);
    k_mean<<<dim3(64, 8), 256, 0, stream>>>(encS, meanB);

    // h0 | c0 = meanB @ WInit^T
    mgemm<64, 64, 32, 32, 6, 0><<<dim3(16, 1), 256, 0, stream>>>(
        meanB, ENC_, WInit, ENC_, hb0, c, 0, 1024, ENC_, bih, bic, nullptr);
    // enc_proj -> ept bf16 [b*196+p][a], XCD-swizzled (A-tile shared blocks co-XCD)
    mgemm<128, 128, 64, 64, 1, 1><<<416, 256, 0, stream>>>(
        encS, ENC_, WeaT, ENC_, ept, nullptr, A_, A_, ENC_, bea, nullptr, nullptr);

    for (int t = 0; t < T_; ++t) {
        ushort16* hcur = (t & 1) ? hb1 : hb0;
        ushort16* hnxt = (t & 1) ? hb0 : hb1;
        // das | beta-gate (MFMA, 40 blocks)
        mgemm<64, 64, 32, 32, 2, 0><<<dim3(40, 1), 256, 0, stream>>>(
            hcur, D_, Whg, D_, das, gate, 0, 2560, D_, bda, bbe, nullptr);
        k_att<<<dim3(64, 2), 512, 0, stream>>>(das, gate, Wfa, bfa, ept, encS,
                                               dlen, ctxg, out, t);
        k_gates<<<256, 256, 0, stream>>>(embB, ctxg, hcur, W2i, gpart, t);
        k_lstm<<<128, 256, 0, stream>>>(gpart, bIH, bHH, dlen, c, hcur, hnxt, histB, t);
    }
    // all preds in one GEMM, XCD-swizzled (B-tile shared blocks co-XCD)
    mgemm<128, 128, 64, 64, 7, 2><<<800, 256, 0, stream>>>(
        histB, D_, WoB, D_, out + OFF_PREDS, nullptr, 0, V_, D_, bout, nullptr,
        dlen);
}

// Round 11
// 1633.458 us; speedup vs baseline: 1.2124x; 1.0147x over previous
//
#include <hip/hip_runtime.h>

#define B_ 64
#define P_ 196
#define ENC_ 2048
#define L_ 20
#define T_ 19
#define A_ 512
#define D_ 512
#define E_ 512
#define V_ 10000

// output offsets (float elements)
#define OFF_PREDS 0
#define OFF_CAPS  12160000
#define OFF_DLEN  12161280
#define OFF_ALPH  12161344
#define OFF_SIDX  12399680

// workspace offsets (bytes) — total ~104.5 MB
#define WS_SORT   0          /* 64 int */
#define WS_DLEN   1024
#define WS_CAPS   2048       /* 64*20 int */
#define WS_DAS    114688     /* 64*512 f32 */
#define WS_GATE   245760     /* 64*2048 f32 */
#define WS_HB0    770048     /* 64*512 bf16 */
#define WS_HB1    835584
#define WS_C      901120     /* 64*512 f32 */
#define WS_CTXG   1032192    /* 64*2048 bf16 */
#define WS_MEANB  1294336    /* 64*2048 bf16 */
#define WS_HIST   1556480    /* 1280*512 bf16 */
#define WS_EMB    2867200    /* 1216*512 bf16 */
#define WS_GPART  4194304    /* 8*64*2048 f32 = 4 MB */
#define WS_EPT    8388608    /* 12544*512 bf16 = 12.85 MB */
#define WS_WEAT   21233664   /* 512*2048 bf16 */
#define WS_WHG    23330816   /* 2560*512 bf16 */
#define WS_W2I    25952256   /* 2048*3072 bf16 */
#define WS_WOB    38535168   /* 10112*512 bf16 */
#define WS_WINIT  48889856   /* 1024*2048 bf16 */
#define WS_ENCS   53084160   /* 12544*2048 bf16 = 51.38 MB -> end 104464384 */

typedef __attribute__((ext_vector_type(8))) short short8v;
typedef __attribute__((ext_vector_type(4))) float f32x4;
typedef unsigned int uint32;
typedef unsigned short ushort16;

__device__ __forceinline__ float ftanh(float x){ float e=__expf(2.f*x); return 1.f-2.f/(e+1.f); }
__device__ __forceinline__ float fsigm(float x){ return 1.f/(1.f+__expf(-x)); }
__device__ __forceinline__ ushort16 f2b(float f){
    uint32 u = __float_as_uint(f);
    uint32 r = (u + 0x7FFFu + ((u >> 16) & 1u)) >> 16;
    return (ushort16)r;
}
__device__ __forceinline__ uint32 pack_b2(float a, float b){
    return (uint32)f2b(a) | ((uint32)f2b(b) << 16);
}
__device__ __forceinline__ float b2f_lo(uint32 w){ return __uint_as_float(w << 16); }
__device__ __forceinline__ float b2f_hi(uint32 w){ return __uint_as_float(w & 0xFFFF0000u); }
__device__ __forceinline__ float b1f(ushort16 x){ return __uint_as_float((uint32)x << 16); }

// ---------------------------------------------------------------- parallel rank sort + meta
__global__ void k_sort(const int* __restrict__ cap_len, const int* __restrict__ captions,
                       float* __restrict__ out, int* __restrict__ wsi)
{
    __shared__ int len_s[B_];
    int tid = threadIdx.x;        // 64 threads
    int len = cap_len[tid];
    len_s[tid] = len;
    __syncthreads();
    int rank = 0;
#pragma unroll
    for (int j = 0; j < B_; ++j) {
        int lj = len_s[j];
        rank += (lj > len) || (lj == len && j < tid);
    }
    wsi[WS_SORT / 4 + rank] = tid;
    wsi[WS_DLEN / 4 + rank] = len - 1;
    out[OFF_SIDX + rank] = (float)tid;
    out[OFF_DLEN + rank] = (float)(len - 1);
#pragma unroll
    for (int l = 0; l < L_; ++l) {
        int cv = captions[tid * L_ + l];
        wsi[WS_CAPS / 4 + rank * L_ + l] = cv;
        out[OFF_CAPS + rank * L_ + l] = (float)cv;
    }
}

// ---------------------------------------------------------------- fused: sorted bf16 enc copy + mean
// grid (64, 8): block (b, e-slice of 256). Reads enc f32 once; writes encS + meanB.
__global__ __launch_bounds__(256) void k_prep_enc(const float* __restrict__ enc,
                                                  const int* __restrict__ sortidx,
                                                  ushort16* __restrict__ encS,
                                                  ushort16* __restrict__ meanB)
{
    int b = blockIdx.x;
    int e = blockIdx.y * 256 + threadIdx.x;
    long sbase = (long)sortidx[b] * P_ * ENC_ + e;
    long dbase = (long)b * P_ * ENC_ + e;
    float s = 0.f;
    for (int p = 0; p < P_; ++p) {
        float v = enc[sbase + (long)p * ENC_];
        s += v;
        encS[dbase + (long)p * ENC_] = f2b(v);
    }
    meanB[b * ENC_ + e] = f2b(s * (1.f / (float)P_));
}

// ---------------------------------------------------------------- merged transpose+cast (5 weights, 1 launch)
// ranges: [0,256) Wea | [256,320) Wda | [320,576) Wbe | [576,832) Wih | [832,1088) Wic
__global__ __launch_bounds__(256) void k_transpose_all(
    const float* __restrict__ Wea, const float* __restrict__ Wda,
    const float* __restrict__ Wbe, const float* __restrict__ Wih,
    const float* __restrict__ Wic,
    ushort16* __restrict__ WeaT, ushort16* __restrict__ Whg,
    ushort16* __restrict__ WInit)
{
    __shared__ float tile[64][65];
    int id = blockIdx.x;
    const float* src; ushort16* dst; int R, C, bx, by;
    if (id < 256)      { src = Wea; dst = WeaT;                R = 2048; C = 512;  int i2 = id;        bx = i2 & 7;  by = i2 >> 3; }
    else if (id < 320) { src = Wda; dst = Whg;                 R = 512;  C = 512;  int i2 = id - 256;  bx = i2 & 7;  by = i2 >> 3; }
    else if (id < 576) { src = Wbe; dst = Whg + 512 * 512;     R = 512;  C = 2048; int i2 = id - 320;  bx = i2 & 31; by = i2 >> 5; }
    else if (id < 832) { src = Wih; dst = WInit;               R = 2048; C = 512;  int i2 = id - 576;  bx = i2 & 7;  by = i2 >> 3; }
    else               { src = Wic; dst = WInit + 512 * 2048;  R = 2048; C = 512;  int i2 = id - 832;  bx = i2 & 7;  by = i2 >> 3; }
    int c0 = bx * 64, r0 = by * 64;
    int lx = threadIdx.x & 63, ly = threadIdx.x >> 6;
#pragma unroll
    for (int i = 0; i < 16; ++i) {
        int r = ly * 16 + i;
        tile[lx][r] = src[(long)(r0 + r) * C + c0 + lx];
    }
    __syncthreads();
#pragma unroll
    for (int i = 0; i < 16; ++i) {
        int cr = ly * 16 + i;
        dst[(long)(c0 + cr) * R + r0 + lx] = f2b(tile[cr][lx]);
    }
}

// ---------------------------------------------------------------- merged small prep: wout | emb | w2i
// ranges: [0,10112) wout rows | [10112,11328) emb rows | [11328,13376) w2i rows
__global__ __launch_bounds__(256) void k_prep_small(
    const float* __restrict__ Wout, const float* __restrict__ embedding,
    const int* __restrict__ caps, const float* __restrict__ WIH,
    const float* __restrict__ WHH,
    ushort16* __restrict__ WoB, ushort16* __restrict__ embB,
    ushort16* __restrict__ W2i)
{
    int id = blockIdx.x;
    if (id < 10112) {
        int r = id, k = threadIdx.x * 2;
        uint32 v = 0;
        if (r < V_) {
            float2 f = *(const float2*)(Wout + (long)r * 512 + k);
            v = pack_b2(f.x, f.y);
        }
        *(uint32*)(WoB + (long)r * 512 + k) = v;
    } else if (id < 11328) {
        int m = id - 10112;                    // m = t*64+b
        int tok = caps[(m & 63) * L_ + (m >> 6)];
        int k = threadIdx.x * 2;
        float2 v = *(const float2*)(embedding + (long)tok * E_ + k);
        *(uint32*)(embB + (long)m * E_ + k) = pack_b2(v.x, v.y);
    } else {
        int r = id - 11328;                    // 0..2047, r = 4d+q
        int d = r >> 2, q = r & 3;
        int n = q * 512 + d;
        for (int cch = threadIdx.x; cch < 384; cch += 256) {
            int kof = cch * 8;
            const float* s = (kof < 2560) ? (WIH + (long)n * 2560 + kof)
                                          : (WHH + (long)n * 512 + (kof - 2560));
            float4 f0 = *(const float4*)s;
            float4 f1 = *(const float4*)(s + 4);
            uint4 v; v.x = pack_b2(f0.x, f0.y); v.y = pack_b2(f0.z, f0.w);
            v.z = pack_b2(f1.x, f1.y); v.w = pack_b2(f1.z, f1.w);
            *(uint4*)(W2i + (long)r * 3072 + kof) = v;
        }
    }
}

// ---------------------------------------------------------------- bf16 MFMA GEMM
// EPI 1: bf16 C = v+bias
// EPI 2: gn<512 -> das=v+bias; else gate=sigmoid(v+bias2)
// EPI 6: gn<512 -> hb=f2b(v+bias); else c=v+bias2
// EPI 7: b=gm&63,tt=gm>>6; tt<T_ guard; preds=(tt<dlen)?v+bias:0
// SWZ 1: enc_proj 1D grid 784=98x8 -> (m<196, n<4), 4 same-A blocks co-XCD
// SWZ 2: pred     1D grid 800 -> (x<79, y<10), same-B blocks co-XCD
template<int BM, int BN, int WM, int WN, int EPI, int SWZ>
__global__ __launch_bounds__(256) void mgemm(
    const ushort16* __restrict__ Amat, int lda1,
    const ushort16* __restrict__ Bmat, int ldb,
    void* __restrict__ Cout, void* __restrict__ Cout2, int ldc, int N, int K,
    const float* __restrict__ bias, const float* __restrict__ bias2,
    const int* __restrict__ dlen)
{
    int bx, by;
    if (SWZ == 1) {
        int id = blockIdx.x;                 // 784 = 98 per XCD x 8 XCDs (exact)
        int xcd = id & 7, idx = id >> 3;     // idx 0..97
        int j = xcd * 98 + idx;              // contiguous j-chunk per XCD
        by = j >> 2;                         // m-tile 0..195 (same-A quad co-XCD)
        bx = j & 3;                          // n-tile 0..3
    } else if (SWZ == 2) {
        int id = blockIdx.x;                 // 800 launched, 790 logical
        bx = (id / 80) * 8 + (id & 7);       // same-bx blocks differ by 8 -> same XCD
        by = (id >> 3) % 10;
        if (bx >= 79) return;
    } else { bx = blockIdx.x; by = blockIdx.y; }

    __shared__ __align__(16) ushort16 As[BM * 64];
    __shared__ __align__(16) ushort16 Bs[BN * 64];
    const int tid = threadIdx.x;
    const int m0 = by * BM, n0 = bx * BN;
    const int lane = tid & 63, wid = tid >> 6;
    constexpr int NWC = BN / WN;
    const int wr = wid / NWC, wc = wid % NWC;
    constexpr int FM = WM / 16, FN = WN / 16;
    f32x4 acc[FM][FN] = {};

    for (int k0 = 0; k0 < K; k0 += 64) {
        for (int i = tid; i < BM * 8; i += 256) {
            int r = i >> 3, ck = i & 7;
            uint4 val = *(const uint4*)(Amat + (long)(m0 + r) * lda1 + k0 + ck * 8);
            int bo = (r * 128 + ck * 16) ^ ((r & 7) << 4);
            *(uint4*)((char*)As + bo) = val;
        }
        for (int i = tid; i < BN * 8; i += 256) {
            int r = i >> 3, ck = i & 7;
            uint4 val = *(const uint4*)(Bmat + (long)(n0 + r) * ldb + k0 + ck * 8);
            int bo = (r * 128 + ck * 16) ^ ((r & 7) << 4);
            *(uint4*)((char*)Bs + bo) = val;
        }
        __syncthreads();
#pragma unroll
        for (int kk = 0; kk < 64; kk += 32) {
            short8v af[FM], bfr[FN];
#pragma unroll
            for (int f = 0; f < FM; ++f) {
                int r = wr * WM + f * 16 + (lane & 15);
                int bo = (r * 128 + (kk + ((lane >> 4) << 3)) * 2) ^ ((r & 7) << 4);
                af[f] = *(const short8v*)((const char*)As + bo);
            }
#pragma unroll
            for (int f = 0; f < FN; ++f) {
                int r = wc * WN + f * 16 + (lane & 15);
                int bo = (r * 128 + (kk + ((lane >> 4) << 3)) * 2) ^ ((r & 7) << 4);
                bfr[f] = *(const short8v*)((const char*)Bs + bo);
            }
#pragma unroll
            for (int fm = 0; fm < FM; ++fm)
#pragma unroll
                for (int fn = 0; fn < FN; ++fn)
                    acc[fm][fn] = __builtin_amdgcn_mfma_f32_16x16x32_bf16(
                        af[fm], bfr[fn], acc[fm][fn], 0, 0, 0);
        }
        __syncthreads();
    }

    int rr = lane >> 4, cc = lane & 15;
#pragma unroll
    for (int fm = 0; fm < FM; ++fm) {
#pragma unroll
        for (int fn = 0; fn < FN; ++fn) {
#pragma unroll
            for (int r = 0; r < 4; ++r) {
                int gm = m0 + wr * WM + fm * 16 + rr * 4 + r;
                int gn = n0 + wc * WN + fn * 16 + cc;
                float v = acc[fm][fn][r];
                if (EPI == 1) {
                    ((ushort16*)Cout)[(long)gm * ldc + gn] = f2b(v + bias[gn]);
                } else if (EPI == 2) {
                    if (gn < 512) ((float*)Cout)[gm * 512 + gn] = v + bias[gn];
                    else ((float*)Cout2)[gm * ENC_ + (gn - 512)] = fsigm(v + bias2[gn - 512]);
                } else if (EPI == 6) {
                    if (gn < 512) ((ushort16*)Cout)[gm * 512 + gn] = f2b(v + bias[gn]);
                    else ((float*)Cout2)[gm * 512 + (gn - 512)] = v + bias2[gn - 512];
                } else if (EPI == 7) {
                    int bq = gm & 63, tt = gm >> 6;
                    if (gn < N && tt < T_)   // tt<T_: rows >=1216 are padding (R8 bug lesson)
                        ((float*)Cout)[((long)bq * T_ + tt) * V_ + gn] =
                            (tt < dlen[bq]) ? v + bias[gn] : 0.f;
                }
            }
        }
    }
}

// ---------------------------------------------------------------- attention: scores+softmax+alpha+ctx
// grid (64, 2), 512 threads: scores+softmax redundant per eg; ctx split by eg (1024 cols each)
__global__ __launch_bounds__(512) void k_att(
    const float* __restrict__ das, const float* __restrict__ gate,
    const float* __restrict__ Wfa, const float* __restrict__ bfa,
    const ushort16* __restrict__ ept, const ushort16* __restrict__ encS,
    const int* __restrict__ dlen,
    ushort16* __restrict__ ctxg, float* __restrict__ out, int t)
{
    int b = blockIdx.x, eg = blockIdx.y;
    int tid = threadIdx.x;
    if (t >= dlen[b]) {
        if (eg == 0 && tid < P_) out[OFF_ALPH + ((long)b * T_ + t) * P_ + tid] = 0.f;
        return;
    }
    __shared__ float al[P_ + 4];
    __shared__ float red[512];
    int lane = tid & 63, wv = tid >> 6;
    // scores: waves split p, lanes split a
    float wf8[8], da8[8];
    {
        const float* wp = Wfa + lane * 8;
        const float* dp = das + b * 512 + lane * 8;
#pragma unroll
        for (int j = 0; j < 8; ++j) { wf8[j] = wp[j]; da8[j] = dp[j]; }
    }
    float b0 = bfa[0];
    for (int p = wv; p < P_; p += 8) {
        uint4 u = *(const uint4*)(ept + ((long)(b * P_ + p)) * 512 + lane * 8);
        float s = 0.f;
        s += wf8[0] * ftanh(b2f_lo(u.x) + da8[0]);
        s += wf8[1] * ftanh(b2f_hi(u.x) + da8[1]);
        s += wf8[2] * ftanh(b2f_lo(u.y) + da8[2]);
        s += wf8[3] * ftanh(b2f_hi(u.y) + da8[3]);
        s += wf8[4] * ftanh(b2f_lo(u.z) + da8[4]);
        s += wf8[5] * ftanh(b2f_hi(u.z) + da8[5]);
        s += wf8[6] * ftanh(b2f_lo(u.w) + da8[6]);
        s += wf8[7] * ftanh(b2f_hi(u.w) + da8[7]);
#pragma unroll
        for (int off = 32; off > 0; off >>= 1) s += __shfl_xor(s, off);
        if (lane == 0) al[p] = s + b0;
    }
    __syncthreads();
    // softmax over 196 (512-thread tree)
    float sc = (tid < P_) ? al[tid] : -1e30f;
    red[tid] = sc;
    __syncthreads();
    for (int s = 256; s > 0; s >>= 1) {
        if (tid < s) red[tid] = fmaxf(red[tid], red[tid + s]);
        __syncthreads();
    }
    float mx = red[0];
    __syncthreads();
    float e = (tid < P_) ? __expf(sc - mx) : 0.f;
    red[tid] = e;
    __syncthreads();
    for (int s = 256; s > 0; s >>= 1) {
        if (tid < s) red[tid] += red[tid + s];
        __syncthreads();
    }
    float inv = 1.f / red[0];
    __syncthreads();
    if (tid < P_) al[tid] = e * inv;
    __syncthreads();
    if (eg == 0 && tid < P_)
        out[OFF_ALPH + ((long)b * T_ + t) * P_ + tid] = al[tid];
    // ctx: 2 bf16 cols per thread from encS, this block's 1024-col slice
    int e0 = eg * 1024 + tid * 2;
    long base = ((long)b * P_) * ENC_ + e0;
    float a0 = 0.f, a1 = 0.f;
#pragma unroll 4
    for (int p = 0; p < P_; ++p) {
        uint32 v = *(const uint32*)(encS + base + (long)p * ENC_);
        float alp = al[p];
        a0 += alp * b2f_lo(v); a1 += alp * b2f_hi(v);
    }
    float2 g2 = *(const float2*)(gate + b * ENC_ + e0);
    *(uint32*)(ctxg + b * ENC_ + e0) = pack_b2(g2.x * a0, g2.y * a1);
}

// ---------------------------------------------------------------- gates GEMM split-K (256 blocks) — R7 proven
__global__ __launch_bounds__(256) void k_gates(
    const ushort16* __restrict__ embB, const ushort16* __restrict__ ctxg,
    const ushort16* __restrict__ hin,  const ushort16* __restrict__ W2i,
    float* __restrict__ gpart, int t)
{
    __shared__ __align__(16) ushort16 As[64 * 64];
    __shared__ __align__(16) ushort16 Bs[64 * 64];
    const int tid = threadIdx.x;
    const int nt = blockIdx.x >> 3, ks = blockIdx.x & 7;
    const int n0 = nt * 64, kbeg = ks * 384;
    const int lane = tid & 63, wid = tid >> 6;
    const int wr = wid >> 1, wc = wid & 1;
    f32x4 acc[2][2] = {};

    for (int k0 = kbeg; k0 < kbeg + 384; k0 += 64) {
        for (int i = tid; i < 512; i += 256) {
            int r = i >> 3, ck = i & 7;
            int kk = k0 + ck * 8;
            const ushort16* src;
            if (kk < 512)       src = embB + ((long)(t * 64 + r)) * 512 + kk;
            else if (kk < 2560) src = ctxg + (long)r * ENC_ + (kk - 512);
            else                src = hin + (long)r * 512 + (kk - 2560);
            uint4 val = *(const uint4*)src;
            int bo = (r * 128 + ck * 16) ^ ((r & 7) << 4);
            *(uint4*)((char*)As + bo) = val;
        }
        for (int i = tid; i < 512; i += 256) {
            int r = i >> 3, ck = i & 7;
            uint4 val = *(const uint4*)(W2i + (long)(n0 + r) * 3072 + k0 + ck * 8);
            int bo = (r * 128 + ck * 16) ^ ((r & 7) << 4);
            *(uint4*)((char*)Bs + bo) = val;
        }
        __syncthreads();
#pragma unroll
        for (int kk = 0; kk < 64; kk += 32) {
            short8v af[2], bfr[2];
#pragma unroll
            for (int f = 0; f < 2; ++f) {
                int r = wr * 32 + f * 16 + (lane & 15);
                int bo = (r * 128 + (kk + ((lane >> 4) << 3)) * 2) ^ ((r & 7) << 4);
                af[f] = *(const short8v*)((const char*)As + bo);
            }
#pragma unroll
            for (int f = 0; f < 2; ++f) {
                int r = wc * 32 + f * 16 + (lane & 15);
                int bo = (r * 128 + (kk + ((lane >> 4) << 3)) * 2) ^ ((r & 7) << 4);
                bfr[f] = *(const short8v*)((const char*)Bs + bo);
            }
#pragma unroll
            for (int fm = 0; fm < 2; ++fm)
#pragma unroll
                for (int fn = 0; fn < 2; ++fn)
                    acc[fm][fn] = __builtin_amdgcn_mfma_f32_16x16x32_bf16(
                        af[fm], bfr[fn], acc[fm][fn], 0, 0, 0);
        }
        __syncthreads();
    }
    int rr = lane >> 4, cc = lane & 15;
#pragma unroll
    for (int fm = 0; fm < 2; ++fm)
#pragma unroll
        for (int fn = 0; fn < 2; ++fn)
#pragma unroll
            for (int r = 0; r < 4; ++r) {
                int gm = wr * 32 + fm * 16 + rr * 4 + r;
                int gn = n0 + wc * 32 + fn * 16 + cc;
                gpart[((long)(ks * 64 + gm)) * ENC_ + gn] = acc[fm][fn][r];
            }
}

// ---------------------------------------------------------------- LSTM pointwise (reduce 8 partials) — R7 proven
__global__ __launch_bounds__(256) void k_lstm(
    const float* __restrict__ gpart,
    const float* __restrict__ bIH, const float* __restrict__ bHH,
    const int* __restrict__ dlen, float* __restrict__ c,
    const ushort16* __restrict__ hin, ushort16* __restrict__ hout,
    ushort16* __restrict__ histB, int t)
{
    int idx = blockIdx.x * 256 + threadIdx.x;   // 128 blocks -> 64 b x 512 d
    int b = idx >> 9, d = idx & 511;
    long off = (long)b * 512 + d;
    if (t < dlen[b]) {
        float s0 = 0.f, s1 = 0.f, s2 = 0.f, s3 = 0.f;
#pragma unroll
        for (int ks = 0; ks < 8; ++ks) {
            float4 gp = *(const float4*)(gpart + ((long)(ks * 64 + b)) * ENC_ + 4 * d);
            s0 += gp.x; s1 += gp.y; s2 += gp.z; s3 += gp.w;
        }
        float g0 = s0 + bIH[d] + bHH[d];
        float g1 = s1 + bIH[512 + d] + bHH[512 + d];
        float g2v = s2 + bIH[1024 + d] + bHH[1024 + d];
        float g3 = s3 + bIH[1536 + d] + bHH[1536 + d];
        float i_ = fsigm(g0), f_ = fsigm(g1), gg = ftanh(g2v), o_ = fsigm(g3);
        float cn = f_ * c[off] + i_ * gg;
        float hn = o_ * ftanh(cn);
        c[off] = cn;
        ushort16 hv = f2b(hn);
        hout[off] = hv;
        histB[((long)(t * 64 + b)) * 512 + d] = hv;
    } else {
        hout[off] = hin[off];
    }
}

// ---------------------------------------------------------------- launch
extern "C" void kernel_launch(void* const* d_in, const int* in_sizes, int n_in,
                              void* d_out, int out_size, void* d_ws, size_t ws_size,
                              hipStream_t stream)
{
    (void)in_sizes; (void)n_in; (void)out_size; (void)ws_size;
    const float* enc      = (const float*)d_in[0];
    const int*   captions = (const int*)d_in[1];
    const int*   caplen   = (const int*)d_in[2];
    const float* Wemb     = (const float*)d_in[3];
    const float* Wea = (const float*)d_in[4];  const float* bea = (const float*)d_in[5];
    const float* Wda = (const float*)d_in[6];  const float* bda = (const float*)d_in[7];
    const float* Wfa = (const float*)d_in[8];  const float* bfa = (const float*)d_in[9];
    const float* Wih = (const float*)d_in[10]; const float* bih = (const float*)d_in[11];
    const float* Wic = (const float*)d_in[12]; const float* bic = (const float*)d_in[13];
    const float* Wbe = (const float*)d_in[14]; const float* bbe = (const float*)d_in[15];
    const float* WIH = (const float*)d_in[16]; const float* bIH = (const float*)d_in[17];
    const float* WHH = (const float*)d_in[18]; const float* bHH = (const float*)d_in[19];
    const float* Wout = (const float*)d_in[20]; const float* bout = (const float*)d_in[21];

    float* out = (float*)d_out;
    char*  ws  = (char*)d_ws;
    int*   wsi = (int*)ws;
    const int* dlen = wsi + WS_DLEN / 4;
    const int* sortidx = wsi + WS_SORT / 4;
    float* das     = (float*)(ws + WS_DAS);
    float* gate    = (float*)(ws + WS_GATE);
    ushort16* hb0  = (ushort16*)(ws + WS_HB0);
    ushort16* hb1  = (ushort16*)(ws + WS_HB1);
    float* c       = (float*)(ws + WS_C);
    ushort16* ctxg = (ushort16*)(ws + WS_CTXG);
    ushort16* meanB= (ushort16*)(ws + WS_MEANB);
    ushort16* histB= (ushort16*)(ws + WS_HIST);
    ushort16* embB = (ushort16*)(ws + WS_EMB);
    float* gpart   = (float*)(ws + WS_GPART);
    ushort16* ept  = (ushort16*)(ws + WS_EPT);
    ushort16* WeaT = (ushort16*)(ws + WS_WEAT);
    ushort16* Whg  = (ushort16*)(ws + WS_WHG);
    ushort16* W2i  = (ushort16*)(ws + WS_W2I);
    ushort16* WoB  = (ushort16*)(ws + WS_WOB);
    ushort16* WInit= (ushort16*)(ws + WS_WINIT);
    ushort16* encS = (ushort16*)(ws + WS_ENCS);

    k_sort<<<1, 64, 0, stream>>>(caplen, captions, out, wsi);
    k_prep_enc<<<dim3(64, 8), 256, 0, stream>>>(enc, sortidx, encS, meanB);
    k_transpose_all<<<1088, 256, 0, stream>>>(Wea, Wda, Wbe, Wih, Wic, WeaT, Whg, WInit);
    k_prep_small<<<13376, 256, 0, stream>>>(Wout, Wemb, wsi + WS_CAPS / 4, WIH, WHH,
                                            WoB, embB, W2i);

    // h0 | c0 = meanB @ WInit^T
    mgemm<64, 64, 32, 32, 6, 0><<<dim3(16, 1), 256, 0, stream>>>(
        meanB, ENC_, WInit, ENC_, hb0, c, 0, 1024, ENC_, bih, bic, nullptr);
    // enc_proj -> ept bf16 [b*196+p][a]: BM=64 x BN=128, 784 blocks (3/CU), XCD-chunked
    mgemm<64, 128, 32, 64, 1, 1><<<784, 256, 0, stream>>>(
        encS, ENC_, WeaT, ENC_, ept, nullptr, A_, A_, ENC_, bea, nullptr, nullptr);

    for (int t = 0; t < T_; ++t) {
        ushort16* hcur = (t & 1) ? hb1 : hb0;
        ushort16* hnxt = (t & 1) ? hb0 : hb1;
        // das | beta-gate (MFMA, 40 blocks)
        mgemm<64, 64, 32, 32, 2, 0><<<dim3(40, 1), 256, 0, stream>>>(
            hcur, D_, Whg, D_, das, gate, 0, 2560, D_, bda, bbe, nullptr);
        k_att<<<dim3(64, 2), 512, 0, stream>>>(das, gate, Wfa, bfa, ept, encS,
                                               dlen, ctxg, out, t);
        k_gates<<<256, 256, 0, stream>>>(embB, ctxg, hcur, W2i, gpart, t);
        k_lstm<<<128, 256, 0, stream>>>(gpart, bIH, bHH, dlen, c, hcur, hnxt, histB, t);
    }
    // all preds in one GEMM, XCD-swizzled (B-tile shared blocks co-XCD)
    mgemm<128, 128, 64, 64, 7, 2><<<800, 256, 0, stream>>>(
        histB, D_, WoB, D_, out + OFF_PREDS, nullptr, 0, V_, D_, bout, nullptr,
        dlen);
}